// Round 1
// baseline (127.302 us; speedup 1.0000x reference)
//
#include <hip/hip_runtime.h>

// CIN (xDeepFM) fused kernel for MI355X (gfx950), bf16 MFMA path.
// B=1024, F=39, D=32; L0: M=256 K=1521 (padded to 1560=39*40, 49 steps of 32);
// L1: M=128 K=4992 (156 steps). 2 batches per block, N=64 columns (b,d).

typedef __bf16 bf16x8 __attribute__((ext_vector_type(8)));
typedef float f32x4 __attribute__((ext_vector_type(4)));

#define NB 2
#define NBLK 512
#define THREADS 256
#define K0STEPS 49
#define K1STEPS 156

__global__ __launch_bounds__(256) void prep_kernel(
    const float* __restrict__ w0, const float* __restrict__ w1,
    __bf16* __restrict__ w0b, __bf16* __restrict__ w1b) {
  int stride = gridDim.x * blockDim.x;
  int tid = blockIdx.x * blockDim.x + threadIdx.x;
  // w0b[blk][o][j]: K reordered as i' = m*40 + n (n<39 valid, else 0); i'>=1560 -> 0
  const int n0 = K0STEPS * 256 * 32;
  for (int idx = tid; idx < n0; idx += stride) {
    int j = idx & 31, o = (idx >> 5) & 255, blk = idx >> 13;
    int ip = blk * 32 + j;
    float v = 0.f;
    if (ip < 1560) {
      unsigned m = (unsigned)ip / 40u;
      unsigned n = (unsigned)ip - m * 40u;
      if (n < 39u) v = w0[o * 1521 + m * 39 + n];
    }
    w0b[idx] = (__bf16)v;
  }
  // w1b[blk][o][j]: natural i = m*128 + n2 (4992 = 156*32 exact)
  const int n1 = K1STEPS * 128 * 32;
  for (int idx = tid; idx < n1; idx += stride) {
    int j = idx & 31, o = (idx >> 5) & 127, blk = idx >> 12;
    int i = blk * 32 + j;
    w1b[idx] = (__bf16)w1[o * 4992 + i];
  }
}

__global__ __launch_bounds__(256, 2) void cin_kernel(
    const float* __restrict__ x,
    const __bf16* __restrict__ w0b, const float* __restrict__ b0,
    const __bf16* __restrict__ w1b, const float* __restrict__ b1,
    float* __restrict__ out) {
  // LDS: 5120 + 32768 + 8192 + 17408 = 63488 B -> 2 blocks/CU
  __shared__ __align__(16) __bf16 xs[NB * 32 * 40];    // [b][d][40] (col 39 zero pad)
  __shared__ __align__(16) __bf16 wbuf[2 * 256 * 32];  // XOR-swizzled w tile, dbuf
  __shared__ __align__(16) __bf16 zsm[2 * 64 * 32];    // XOR-swizzled z tile [col][k], dbuf
  __shared__ __align__(16) __bf16 h1[NB * 32 * 136];   // [b][d][136] h1a (bf16)

  const int t = threadIdx.x;
  const int bb = blockIdx.x * NB;
  const int w = t >> 6;          // wave id
  const int l15 = t & 15;
  const int lhi = (t >> 4) & 3;
  const int col = t & 63;        // zgen column = (b,d)
  const int kg = t >> 6;         // zgen k-group
  const int zb = col >> 5, zd = col & 31;
  const int xrow = (zb * 32 + zd) * 40;
  const int hrow = (zb * 32 + zd) * 136;
  const int zwoff = col * 32 + ((kg ^ ((col >> 1) & 3)) * 8);

  // ---- load x[b] -> xs transposed [b][d][m], bf16 ----
  for (int idx = t; idx < NB * 39 * 32; idx += THREADS) {
    int b = idx / 1248; int rem = idx - b * 1248;
    int m = rem >> 5; int d = rem & 31;
    xs[(b * 32 + d) * 40 + m] = (__bf16)x[(bb + b) * 1248 + rem];
  }
  if (t < NB * 32) xs[t * 40 + 39] = (__bf16)0.f;  // zero the m=39 pad (NaN guard)
  __syncthreads();

  // frag LDS offsets (element units), swizzle baked in
  int aoff0[4], boff[4];
#pragma unroll
  for (int mt = 0; mt < 4; ++mt) {
    int row = w * 64 + mt * 16 + l15;
    aoff0[mt] = row * 32 + ((lhi ^ ((row >> 1) & 3)) * 8);
  }
#pragma unroll
  for (int nt = 0; nt < 4; ++nt) {
    int cc = nt * 16 + l15;
    boff[nt] = cc * 32 + ((lhi ^ ((cc >> 1) & 3)) * 8);
  }

  // ================= LAYER 0 =================
  f32x4 acc[4][4] = {};

  auto stage0 = [&](int s, int nxt) {
    uint4 wr[4];
    const uint4* gs = (const uint4*)w0b + s * 1024 + t;
#pragma unroll
    for (int r = 0; r < 4; ++r) wr[r] = gs[r * 256];
    // z generation: i' = s*32 + kg*8 + jj, all 8 share m (40 % 8 == 0)
    int i0 = s * 32 + kg * 8;
    bf16x8 vz;
    if (i0 < 1560) {
      unsigned m = (unsigned)i0 / 40u;
      unsigned nb = (unsigned)i0 - m * 40u;
      float xm = (float)xs[xrow + m];
      bf16x8 xn = *(const bf16x8*)&xs[xrow + nb];
#pragma unroll
      for (int jj = 0; jj < 8; ++jj) vz[jj] = (__bf16)(xm * (float)xn[jj]);
    } else {
#pragma unroll
      for (int jj = 0; jj < 8; ++jj) vz[jj] = (__bf16)0.f;
    }
    *(bf16x8*)&zsm[nxt * 2048 + zwoff] = vz;
#pragma unroll
    for (int r = 0; r < 4; ++r) {
      int q = t + r * 256; int row = q >> 2;
      int u = (q & 3) ^ ((row >> 1) & 3);
      *(uint4*)&wbuf[nxt * 8192 + row * 32 + u * 8] = wr[r];
    }
  };
  auto compute0 = [&](int curb) {
    bf16x8 af[4], bfr[4];
#pragma unroll
    for (int mt = 0; mt < 4; ++mt) af[mt] = *(const bf16x8*)&wbuf[curb * 8192 + aoff0[mt]];
#pragma unroll
    for (int nt = 0; nt < 4; ++nt) bfr[nt] = *(const bf16x8*)&zsm[curb * 2048 + boff[nt]];
#pragma unroll
    for (int mt = 0; mt < 4; ++mt)
#pragma unroll
      for (int nt = 0; nt < 4; ++nt)
        acc[mt][nt] = __builtin_amdgcn_mfma_f32_16x16x32_bf16(af[mt], bfr[nt], acc[mt][nt], 0, 0, 0);
  };

  stage0(0, 0);
  __syncthreads();
  int cur = 0;
  for (int s = 0; s < K0STEPS; ++s) {
    if (s + 1 < K0STEPS) stage0(s + 1, cur ^ 1);
    compute0(cur);
    __syncthreads();
    cur ^= 1;
  }

  // ---- epilogue 0: bias+relu; o<128 -> h1a LDS; o>=128 -> d-sum -> out[ch 0..127]
  if (w < 2) {
#pragma unroll
    for (int mt = 0; mt < 4; ++mt) {
#pragma unroll
      for (int nt = 0; nt < 4; ++nt) {
        int b = nt >> 1; int d = (nt & 1) * 16 + l15;
        int hbase = (b * 32 + d) * 136;
#pragma unroll
        for (int r = 0; r < 4; ++r) {
          int o = w * 64 + mt * 16 + lhi * 4 + r;
          float v = fmaxf(acc[mt][nt][r] + b0[o], 0.f);
          h1[hbase + o] = (__bf16)v;
        }
      }
    }
  } else {
#pragma unroll
    for (int mt = 0; mt < 4; ++mt) {
#pragma unroll
      for (int r = 0; r < 4; ++r) {
        int o = w * 64 + mt * 16 + lhi * 4 + r;  // 128..255
        float bias = b0[o];
        float sb0 = 0.f, sb1 = 0.f;
#pragma unroll
        for (int nt = 0; nt < 4; ++nt) {
          float v = fmaxf(acc[mt][nt][r] + bias, 0.f);
          v += __shfl_xor(v, 1); v += __shfl_xor(v, 2);
          v += __shfl_xor(v, 4); v += __shfl_xor(v, 8);
          if (nt < 2) sb0 += v; else sb1 += v;
        }
        if (l15 == 0) {
          out[(bb + 0) * 256 + (o - 128)] = sb0;
          out[(bb + 1) * 256 + (o - 128)] = sb1;
        }
      }
    }
  }
  __syncthreads();  // h1a visible; wbuf/zsm free

  // ================= LAYER 1 =================
  int aoff1[2];
#pragma unroll
  for (int mt = 0; mt < 2; ++mt) {
    int row = w * 32 + mt * 16 + l15;
    aoff1[mt] = row * 32 + ((lhi ^ ((row >> 1) & 3)) * 8);
  }
  f32x4 acc2[2][4] = {};

  auto stage1 = [&](int s, int nxt) {
    uint4 wr[2];
    const uint4* gs = (const uint4*)w1b + s * 512 + t;
#pragma unroll
    for (int r = 0; r < 2; ++r) wr[r] = gs[r * 256];
    int i0 = s * 32 + kg * 8;
    int m = i0 >> 7, nb = i0 & 127;  // 128 % 8 == 0: same m for all 8
    float xm = (float)xs[xrow + m];
    bf16x8 hv = *(const bf16x8*)&h1[hrow + nb];
    bf16x8 vz;
#pragma unroll
    for (int jj = 0; jj < 8; ++jj) vz[jj] = (__bf16)(xm * (float)hv[jj]);
    *(bf16x8*)&zsm[nxt * 2048 + zwoff] = vz;
#pragma unroll
    for (int r = 0; r < 2; ++r) {
      int q = t + r * 256; int row = q >> 2;
      int u = (q & 3) ^ ((row >> 1) & 3);
      *(uint4*)&wbuf[nxt * 8192 + row * 32 + u * 8] = wr[r];
    }
  };
  auto compute1 = [&](int curb) {
    bf16x8 af[2], bfr[4];
#pragma unroll
    for (int mt = 0; mt < 2; ++mt) af[mt] = *(const bf16x8*)&wbuf[curb * 8192 + aoff1[mt]];
#pragma unroll
    for (int nt = 0; nt < 4; ++nt) bfr[nt] = *(const bf16x8*)&zsm[curb * 2048 + boff[nt]];
#pragma unroll
    for (int mt = 0; mt < 2; ++mt)
#pragma unroll
      for (int nt = 0; nt < 4; ++nt)
        acc2[mt][nt] = __builtin_amdgcn_mfma_f32_16x16x32_bf16(af[mt], bfr[nt], acc2[mt][nt], 0, 0, 0);
  };

  stage1(0, 0);
  __syncthreads();
  cur = 0;
  for (int s = 0; s < K1STEPS; ++s) {
    if (s + 1 < K1STEPS) stage1(s + 1, cur ^ 1);
    compute1(cur);
    __syncthreads();
    cur ^= 1;
  }

  // ---- epilogue 1: bias+relu, d-sum -> out[ch 128..255]
#pragma unroll
  for (int mt = 0; mt < 2; ++mt) {
#pragma unroll
    for (int r = 0; r < 4; ++r) {
      int o = w * 32 + mt * 16 + lhi * 4 + r;  // 0..127
      float bias = b1[o];
      float sb0 = 0.f, sb1 = 0.f;
#pragma unroll
      for (int nt = 0; nt < 4; ++nt) {
        float v = fmaxf(acc2[mt][nt][r] + bias, 0.f);
        v += __shfl_xor(v, 1); v += __shfl_xor(v, 2);
        v += __shfl_xor(v, 4); v += __shfl_xor(v, 8);
        if (nt < 2) sb0 += v; else sb1 += v;
      }
      if (l15 == 0) {
        out[(bb + 0) * 256 + 128 + o] = sb0;
        out[(bb + 1) * 256 + 128 + o] = sb1;
      }
    }
  }
}

extern "C" void kernel_launch(void* const* d_in, const int* in_sizes, int n_in,
                              void* d_out, int out_size, void* d_ws, size_t ws_size,
                              hipStream_t stream) {
  const float* x  = (const float*)d_in[0];
  const float* w0 = (const float*)d_in[1];
  const float* b0 = (const float*)d_in[2];
  const float* w1 = (const float*)d_in[3];
  const float* b1 = (const float*)d_in[4];
  float* out = (float*)d_out;

  __bf16* w0b = (__bf16*)d_ws;                 // 49*256*32 bf16 = 802816 B
  __bf16* w1b = w0b + K0STEPS * 256 * 32;      // 156*128*32 bf16 = 1277952 B

  prep_kernel<<<256, 256, 0, stream>>>(w0, w1, w0b, w1b);
  cin_kernel<<<NBLK, THREADS, 0, stream>>>(x, w0b, b0, w1b, b1, out);
}

// Round 2
// 104.650 us; speedup vs baseline: 1.2165x; 1.2165x over previous
//
#include <hip/hip_runtime.h>

// CIN (xDeepFM) fused kernel for MI355X (gfx950), bf16 MFMA path, round 2.
// B=1024, F=39, D=32; L0: M=256 K=1521 (padded to 1600=50*32 steps, m=39 row zero);
// L1 REASSOCIATED: out1[o,c] = sum_m x[m,c] * (W1_m(128x128) @ h(128x64))[o,c]
//   -> B-operand (h) persistent in 64 VGPRs, zero LDS / zero barriers in L1 loop.
// A-operands (weights) loaded directly from global (L2-resident), reg-dbuf prefetch.

typedef __bf16 bf16x8 __attribute__((ext_vector_type(8)));
typedef float f32x4 __attribute__((ext_vector_type(4)));

#define NB 2
#define NBLK 512
#define THREADS 256
#define K0STEPS 50   // 50*32 = 1600 >= 39*40; steps with m=39 contribute 0

__global__ __launch_bounds__(256) void prep_kernel(
    const float* __restrict__ w0, const float* __restrict__ w1,
    __bf16* __restrict__ w0b, __bf16* __restrict__ w1p) {
  int stride = gridDim.x * blockDim.x;
  int tid = blockIdx.x * blockDim.x + threadIdx.x;
  // w0b[blk][o][j]: K reordered as i' = m*40 + n (n<39 valid, else 0); i'>=1560 -> 0
  const int n0 = K0STEPS * 256 * 32;
  for (int idx = tid; idx < n0; idx += stride) {
    int j = idx & 31, o = (idx >> 5) & 255, blk = idx >> 13;
    int ip = blk * 32 + j;
    float v = 0.f;
    if (ip < 1560) {
      unsigned m = (unsigned)ip / 40u;
      unsigned n = (unsigned)ip - m * 40u;
      if (n < 39u) v = w0[o * 1521 + m * 39 + n];
    }
    w0b[idx] = (__bf16)v;
  }
  // w1p[((m*4+ks)*128 + o)*32 + j] = w1[o][m*128 + ks*32 + j]
  const int n1 = 39 * 4 * 128 * 32;
  for (int idx = tid; idx < n1; idx += stride) {
    int j = idx & 31, o = (idx >> 5) & 127, q = idx >> 12;
    int ks = q & 3, m = q >> 2;
    w1p[idx] = (__bf16)w1[o * 4992 + m * 128 + ks * 32 + j];
  }
}

__global__ __launch_bounds__(256, 2) void cin_kernel(
    const float* __restrict__ x,
    const __bf16* __restrict__ w0b, const float* __restrict__ b0,
    const __bf16* __restrict__ w1p, const float* __restrict__ b1,
    float* __restrict__ out) {
  // LDS: 5120 + 8192 + 17408 = 30720 B
  __shared__ __align__(16) __bf16 xs[NB * 32 * 40];    // [c=(b,d)][40] (m=39 slot zero)
  __shared__ __align__(16) __bf16 zsm[2 * 64 * 32];    // XOR-swizzled z tile [col][k], dbuf
  __shared__ __align__(16) __bf16 h1[NB * 32 * 136];   // [c][136] h1a (bf16), stride 17*16B

  const int t = threadIdx.x;
  const int bb = blockIdx.x * NB;
  const int w = t >> 6;          // wave id
  const int l15 = t & 15;
  const int lhi = (t >> 4) & 3;
  const int col = t & 63;        // zgen column = (b,d)
  const int kg = t >> 6;         // zgen k-group
  const int zwoff = col * 32 + ((kg ^ ((col >> 1) & 3)) * 8);

  // ---- load x[b] -> xs transposed [c][m], bf16 ----
  for (int idx = t; idx < NB * 39 * 32; idx += THREADS) {
    int b = idx / 1248; int rem = idx - b * 1248;
    int m = rem >> 5; int d = rem & 31;
    xs[(b * 32 + d) * 40 + m] = (__bf16)x[(bb + b) * 1248 + rem];
  }
  if (t < NB * 32) xs[t * 40 + 39] = (__bf16)0.f;  // zero the m=39 pad
  __syncthreads();

  // B-frag LDS offsets (element units), swizzle baked in
  int boff[4];
#pragma unroll
  for (int nt = 0; nt < 4; ++nt) {
    int cc = nt * 16 + l15;
    boff[nt] = cc * 32 + ((lhi ^ ((cc >> 1) & 3)) * 8);
  }

  // ================= LAYER 0 (direct z-GEMM, A from global) =================
  f32x4 acc[4][4] = {};

  auto loadA0 = [&](int s, bf16x8 (&af)[4]) {
#pragma unroll
    for (int mt = 0; mt < 4; ++mt) {
      int o = w * 64 + mt * 16 + l15;
      af[mt] = *(const bf16x8*)(w0b + s * 8192 + o * 32 + lhi * 8);
    }
  };
  auto zgen0 = [&](int s, int buf) {
    int i0 = s * 32 + kg * 8;
    unsigned m = (unsigned)i0 / 40u;
    unsigned nb = (unsigned)i0 - m * 40u;
    float xm = (float)xs[col * 40 + m];          // m==39 -> 0 -> z==0
    bf16x8 xn = *(const bf16x8*)&xs[col * 40 + nb];
    bf16x8 vz;
#pragma unroll
    for (int jj = 0; jj < 8; ++jj) vz[jj] = (__bf16)(xm * (float)xn[jj]);
    *(bf16x8*)&zsm[buf * 2048 + zwoff] = vz;
  };
  auto compute0 = [&](int buf, bf16x8 (&af)[4]) {
    bf16x8 bfr[4];
#pragma unroll
    for (int nt = 0; nt < 4; ++nt) bfr[nt] = *(const bf16x8*)&zsm[buf * 2048 + boff[nt]];
#pragma unroll
    for (int mt = 0; mt < 4; ++mt)
#pragma unroll
      for (int nt = 0; nt < 4; ++nt)
        acc[mt][nt] = __builtin_amdgcn_mfma_f32_16x16x32_bf16(af[mt], bfr[nt], acc[mt][nt], 0, 0, 0);
  };

  bf16x8 afA[4], afB[4];
  loadA0(0, afA);
  zgen0(0, 0);
  __syncthreads();
  for (int s = 0; s < K0STEPS; s += 2) {
    loadA0(s + 1, afB);
    zgen0(s + 1, 1);
    compute0(0, afA);
    __syncthreads();
    if (s + 2 < K0STEPS) { loadA0(s + 2, afA); zgen0(s + 2, 0); }
    compute0(1, afB);
    __syncthreads();
  }

  // ---- epilogue 0: bias+relu; o<128 -> h1a LDS; o>=128 -> d-sum -> out[ch 0..127]
  if (w < 2) {
#pragma unroll
    for (int mt = 0; mt < 4; ++mt) {
#pragma unroll
      for (int nt = 0; nt < 4; ++nt) {
        int c = nt * 16 + l15;
        int hbase = c * 136;
#pragma unroll
        for (int r = 0; r < 4; ++r) {
          int o = w * 64 + mt * 16 + lhi * 4 + r;
          float v = fmaxf(acc[mt][nt][r] + b0[o], 0.f);
          h1[hbase + o] = (__bf16)v;
        }
      }
    }
  } else {
#pragma unroll
    for (int mt = 0; mt < 4; ++mt) {
#pragma unroll
      for (int r = 0; r < 4; ++r) {
        int o = w * 64 + mt * 16 + lhi * 4 + r;  // 128..255
        float bias = b0[o];
        float sb0 = 0.f, sb1 = 0.f;
#pragma unroll
        for (int nt = 0; nt < 4; ++nt) {
          float v = fmaxf(acc[mt][nt][r] + bias, 0.f);
          v += __shfl_xor(v, 1); v += __shfl_xor(v, 2);
          v += __shfl_xor(v, 4); v += __shfl_xor(v, 8);
          if (nt < 2) sb0 += v; else sb1 += v;
        }
        if (l15 == 0) {
          out[(bb + 0) * 256 + (o - 128)] = sb0;
          out[(bb + 1) * 256 + (o - 128)] = sb1;
        }
      }
    }
  }
  __syncthreads();  // h1a visible

  // ================= LAYER 1 (reassociated, barrier-free) =================
  // hf[ks][nt]: persistent B fragments of h (128 x 64), 64 VGPRs
  bf16x8 hf[4][4];
#pragma unroll
  for (int ks = 0; ks < 4; ++ks)
#pragma unroll
    for (int nt = 0; nt < 4; ++nt)
      hf[ks][nt] = *(const bf16x8*)&h1[(nt * 16 + l15) * 136 + ks * 32 + lhi * 8];

  f32x4 acc2[2][4] = {};

  auto loadA1 = [&](int m, bf16x8 (&wf)[4][2]) {
#pragma unroll
    for (int ks = 0; ks < 4; ++ks)
#pragma unroll
      for (int mt = 0; mt < 2; ++mt) {
        int o = w * 32 + mt * 16 + l15;
        wf[ks][mt] = *(const bf16x8*)(w1p + ((m * 4 + ks) * 128 + o) * 32 + lhi * 8);
      }
  };
  auto computeM = [&](int m, bf16x8 (&wf)[4][2]) {
    float xmv[4];
#pragma unroll
    for (int nt = 0; nt < 4; ++nt) xmv[nt] = (float)xs[(nt * 16 + l15) * 40 + m];
    f32x4 Y[2][4];
#pragma unroll
    for (int ks = 0; ks < 4; ++ks)
#pragma unroll
      for (int mt = 0; mt < 2; ++mt)
#pragma unroll
        for (int nt = 0; nt < 4; ++nt) {
          f32x4 cin = (ks == 0) ? (f32x4){0.f, 0.f, 0.f, 0.f} : Y[mt][nt];
          Y[mt][nt] = __builtin_amdgcn_mfma_f32_16x16x32_bf16(wf[ks][mt], hf[ks][nt], cin, 0, 0, 0);
        }
#pragma unroll
    for (int mt = 0; mt < 2; ++mt)
#pragma unroll
      for (int nt = 0; nt < 4; ++nt)
#pragma unroll
        for (int r = 0; r < 4; ++r)
          acc2[mt][nt][r] += xmv[nt] * Y[mt][nt][r];
  };

  bf16x8 wfA[4][2], wfB[4][2];
  loadA1(0, wfA);
  loadA1(1, wfB);
  for (int m = 0; m < 38; m += 2) {
    computeM(m, wfA);
    if (m + 2 < 39) loadA1(m + 2, wfA);
    computeM(m + 1, wfB);
    if (m + 3 < 39) loadA1(m + 3, wfB);
  }
  computeM(38, wfA);

  // ---- epilogue 1: bias+relu, d-sum -> out[ch 128..255]
#pragma unroll
  for (int mt = 0; mt < 2; ++mt) {
#pragma unroll
    for (int r = 0; r < 4; ++r) {
      int o = w * 32 + mt * 16 + lhi * 4 + r;  // 0..127
      float bias = b1[o];
      float sb0 = 0.f, sb1 = 0.f;
#pragma unroll
      for (int nt = 0; nt < 4; ++nt) {
        float v = fmaxf(acc2[mt][nt][r] + bias, 0.f);
        v += __shfl_xor(v, 1); v += __shfl_xor(v, 2);
        v += __shfl_xor(v, 4); v += __shfl_xor(v, 8);
        if (nt < 2) sb0 += v; else sb1 += v;
      }
      if (l15 == 0) {
        out[(bb + 0) * 256 + 128 + o] = sb0;
        out[(bb + 1) * 256 + 128 + o] = sb1;
      }
    }
  }
}

extern "C" void kernel_launch(void* const* d_in, const int* in_sizes, int n_in,
                              void* d_out, int out_size, void* d_ws, size_t ws_size,
                              hipStream_t stream) {
  const float* x  = (const float*)d_in[0];
  const float* w0 = (const float*)d_in[1];
  const float* b0 = (const float*)d_in[2];
  const float* w1 = (const float*)d_in[3];
  const float* b1 = (const float*)d_in[4];
  float* out = (float*)d_out;

  __bf16* w0b = (__bf16*)d_ws;                 // 50*256*32 bf16 = 819200 B
  __bf16* w1p = w0b + K0STEPS * 256 * 32;      // 39*4*128*32 bf16 = 1277952 B

  prep_kernel<<<256, 256, 0, stream>>>(w0, w1, w0b, w1p);
  cin_kernel<<<NBLK, THREADS, 0, stream>>>(x, w0b, b0, w1p, b1, out);
}